// Round 5
// baseline (1055.844 us; speedup 1.0000x reference)
//
#include <hip/hip_runtime.h>
#include <hip/hip_bf16.h>

// LSTM2: B=1024, T=1024, H=64. R21: R20 (758us, decoupled P/Q flag
// pipelines) + critical-chain surgery. R18/R20 proved the kernel is
// chain-latency-bound (1776cy/step; pipe-work and barrier changes ~nil).
// Changes vs R20 (protocol/flags/ring identical):
//  (1) scr1/scr2 LDS roundtrip DELETED. R13 gate-interleaved A rows give
//      D row = quad*4+reg -> lane (quad,m) holds ALL 4 gates (i,f,g,o =
//      regs 0..3) of unit 16gw+4q+quad, batch m. Cells computed fully
//      in-register on lanes m<NBat (4 independent cells/lane, c-state in
//      cst[4]); h written straight to h1ring/h2buf. -180cy chain, kills
//      remaining bank conflicts.
//  (2) MFMA chains flattened to depth 1: independent k-half MFMAs summed
//      with vector adds (was 2-deep dependent). -1 MFMA latency.
//  (3) acc-init (x*wx+b) hoisted ABOVE the poll (reads only static xs).
//  (4) head partials per-lane: Q lane writes its own sum_q h*wl to
//      headp[par][batch][gw*4+quad]; w4 finalize sums 16 floats via
//      4x ds_read_b128 (replaces per-wave DPP chain on the Q tail).
// Protocol (audited R19/R20): h1ring 4-deep, P<=3 ahead; flg[0..3]=pf,
// flg[4..7]=qf, lane-0 publish after data writes (same-wave DS in-order);
// P(t): min(pf)>=t && min(qf)>=t-3. Q(u): min(pf)>=u+1 && min(qf)>=u.
// Tail: w4 polls min(qf)>=Tt before reading step-(Tt-1) head partials.
// Layouts (m89/m91/m120): A[m=lane&15][k=(lane>>4)*8+j],
// B[k=(lane>>4)*8+j][n=lane&15], C/D: row=(lane>>4)*4+reg, col=lane&15.

typedef _Float16 f16x8 __attribute__((ext_vector_type(8)));
typedef float    f32x4 __attribute__((ext_vector_type(4)));

namespace {
constexpr int Bb = 1024;
constexpr int Tt = 1024;
constexpr int NBat = 4;    // batches per block
constexpr int HSTR = 72;   // f16 stride per batch row of h
constexpr int XSTR = 1025; // f32 stride per batch row of x

// Pre-scaled activations: gate rows of W/b folded with -log2e (i,f,o) and
// -2log2e (g) at load, so no input multiply here.
__device__ __forceinline__ float sigm_pre(float a) {   // a = -1.4427*x
    return __builtin_amdgcn_rcpf(1.0f + __builtin_amdgcn_exp2f(a));
}
__device__ __forceinline__ float tanh_pre(float a) {   // a = -2.8854*x
    return fmaf(2.0f, __builtin_amdgcn_rcpf(1.0f + __builtin_amdgcn_exp2f(a)), -1.0f);
}
__device__ __forceinline__ float tanh_f(float x) {     // unscaled input (c-path)
    float e = __builtin_amdgcn_exp2f(-2.8853900817779268f * x);
    return fmaf(2.0f, __builtin_amdgcn_rcpf(1.0f + e), -1.0f);
}
// Dtype sniff (proven R2-R20).
__device__ __forceinline__ bool detect_f32(const void* w) {
    const unsigned short* p = (const unsigned short*)w;
    int sane = 0;
    for (int i = 0; i < 64; ++i) {
        int e = (p[2 * i] >> 7) & 0xFF;
        if (e >= 107 && e <= 129) ++sane;
    }
    return sane < 32;
}
__device__ __forceinline__ float ld(const void* p, int i, bool f32) {
    return f32 ? ((const float*)p)[i]
               : __bfloat162float(((const __hip_bfloat16*)p)[i]);
}
__device__ __forceinline__ void st(void* p, int i, float v, bool f32) {
    if (f32) ((float*)p)[i] = v;
    else     ((__hip_bfloat16*)p)[i] = __float2bfloat16(v);
}
// Lane-parallel spin: lane i watches flg[i&7]; P-flags (idx<4) against tp,
// Q-flags against tq. One broadcast ds_read_b32 per spin, __all ballot.
__device__ __forceinline__ void poll_flags(const int* f, int tp, int tq, int lane) {
    const int idx = lane & 7;
    const int thr = (idx < 4) ? tp : tq;
    for (;;) {
        int v = ((const volatile int*)f)[idx];
        if (__all(v >= thr)) break;
    }
    __builtin_amdgcn_sched_barrier(0);
    asm volatile("" ::: "memory");
}
} // namespace

__global__ __launch_bounds__(512, 1) void lstm2_kernel(
    const void* __restrict__ x,      // [B, T]
    const void* __restrict__ w_ih1,  // [256, 1]
    const void* __restrict__ w_hh1,  // [256, 64]
    const void* __restrict__ b_ih1,  // [256]
    const void* __restrict__ b_hh1,  // [256]
    const void* __restrict__ w_ih2,  // [256, 64]
    const void* __restrict__ w_hh2,  // [256, 64]
    const void* __restrict__ b_ih2,  // [256]
    const void* __restrict__ b_hh2,  // [256]
    const void* __restrict__ w_lin,  // [1, 64]
    const void* __restrict__ b_lin,  // [1]
    void* __restrict__ out)          // [B, T]
{
    const int tid  = threadIdx.x;
    const int lane = tid & 63;
    const int w    = tid >> 6;       // wave 0..7
    const int gw   = w & 3;          // group-local wave -> unit group 16gw..
    const bool isP = w < 4;          // P: L1 recurrence; Q: L2 pipeline
    const int m    = lane & 15;      // MFMA col (batch; valid m<NBat)
    const int quad = lane >> 4;
    const int bb   = blockIdx.x * NBat;

    const bool f32 = detect_f32(w_hh1);

    __shared__ float                  xs[NBat * XSTR];
    __shared__ __align__(16) _Float16 h1ring[4][16 * HSTR]; // 4-deep ring
    __shared__ __align__(16) _Float16 h2buf[2][16 * HSTR];  // parity (Q-only)
    __shared__ __align__(16) float    headp[2][NBat][16];   // [par][batch][gw*4+quad]
    __shared__ float                  outbuf[NBat * Tt];    // staged outputs
    __shared__ int                    flg[8];               // 0..3 pf, 4..7 qf

    // ---- stage x + zero h buffers (rows >= NBat stay 0 forever) ----
    for (int i = tid; i < NBat * 1024; i += 512)
        xs[(i >> 10) * XSTR + (i & 1023)] = ld(x, (bb + (i >> 10)) * Tt + (i & 1023), f32);
    for (int i = tid; i < 16 * HSTR; i += 512) {
        h1ring[0][i] = (_Float16)0; h1ring[1][i] = (_Float16)0;
        h1ring[2][i] = (_Float16)0; h1ring[3][i] = (_Float16)0;
        h2buf[0][i] = (_Float16)0;  h2buf[1][i] = (_Float16)0;
    }
    if (tid < 8) flg[tid] = 0;

    // ---- A-fragments, gate-interleaved rows (R13), activation-scale folded ----
    // tile row (lane&15) = 4*u_loc + g -> mem row 64*g + 16*gw + 4q + u_loc
    const int arow = lane & 15;
    const int g_ld = arow & 3;
    const int u_ld = arow >> 2;
    const float scA = (g_ld == 2) ? -2.8853900817779268f : -1.4426950408889634f;
    f16x8 wfA[4][2], wfB[4][2];   // P: wfA=W1 (wfB zero); Q: wfA=W2, wfB=W3
    {
        const void* MA = isP ? w_hh1 : w_ih2;
#pragma unroll
        for (int q = 0; q < 4; ++q) {
            const int row = 64 * g_ld + 16 * gw + 4 * q + u_ld;
#pragma unroll
            for (int s = 0; s < 2; ++s) {
                const int base = row * 64 + 32 * s + quad * 8;
                if (f32) {
                    const float* A = (const float*)MA;
                    const float* B = (const float*)w_hh2;
#pragma unroll
                    for (int j = 0; j < 8; ++j) {
                        wfA[q][s][j] = (_Float16)(scA * A[base + j]);
                        wfB[q][s][j] = isP ? (_Float16)0.0f
                                           : (_Float16)(scA * B[base + j]);
                    }
                } else {
                    const __hip_bfloat16* A = (const __hip_bfloat16*)MA;
                    const __hip_bfloat16* B = (const __hip_bfloat16*)w_hh2;
#pragma unroll
                    for (int j = 0; j < 8; ++j) {
                        wfA[q][s][j] = (_Float16)(scA * __bfloat162float(A[base + j]));
                        wfB[q][s][j] = isP ? (_Float16)0.0f
                                           : (_Float16)(scA * __bfloat162float(B[base + j]));
                    }
                }
            }
        }
    }
    // bias / wx per (tile q, gate r): D row r of tile q = gate r, unit 16gw+4q+quad
    f32x4 bv[4], wxv[4];
#pragma unroll
    for (int q = 0; q < 4; ++q)
#pragma unroll
        for (int r = 0; r < 4; ++r) {
            const int row = 64 * r + 16 * gw + 4 * q + quad;
            const float sg = (r == 2) ? -2.8853900817779268f : -1.4426950408889634f;
            bv[q][r] = sg * (isP ? (ld(b_ih1, row, f32) + ld(b_hh1, row, f32))
                                 : (ld(b_ih2, row, f32) + ld(b_hh2, row, f32)));
            wxv[q][r] = isP ? sg * ld(w_ih1, row, f32) : 0.0f;
        }
    // head weights per owned unit (Q): unit 16gw+4q+quad
    float wlv[4];
#pragma unroll
    for (int q = 0; q < 4; ++q) wlv[q] = ld(w_lin, 16 * gw + 4 * q + quad, f32);
    const float blin = ld(b_lin, 0, f32);
    // per-lane owned-unit h write base: [batch m][unit 16gw + 4q + quad]
    const int hwbase = m * HSTR + 16 * gw + quad;
    float cst[4] = {0.0f, 0.0f, 0.0f, 0.0f};   // c-state per owned unit
    __syncthreads();   // xs + zeroed bufs + flags visible

    if (isP) {
        // ================= P: L1 recurrence, self-paced =================
        f16x8 pa0{}, pa1{};
#pragma unroll 4
        for (int t = 0; t < Tt; ++t) {
            // acc-init before poll: reads only static xs/regs
            const float xt = xs[(m & (NBat - 1)) * XSTR + t];
            f32x4 ai[4];
#pragma unroll
            for (int q = 0; q < 4; ++q)
#pragma unroll
                for (int r = 0; r < 4; ++r)
                    ai[q][r] = fmaf(xt, wxv[q][r], bv[q][r]);
            poll_flags(flg, t, t - 3, lane);   // group sync + ring-not-full
            f32x4 acc[4];
            if (t > 0) {
                const _Float16* hp = h1ring[(t - 1) & 3] + m * HSTR;
                if (m < NBat) {       // masked read: only valid batches
                    pa0 = *(const f16x8*)(hp + quad * 8);
                    pa1 = *(const f16x8*)(hp + 32 + quad * 8);
                }
                __builtin_amdgcn_s_setprio(1);
#pragma unroll
                for (int q = 0; q < 4; ++q) {   // depth-1: independent k-halves
                    f32x4 p0 = __builtin_amdgcn_mfma_f32_16x16x32_f16(wfA[q][0], pa0, ai[q], 0, 0, 0);
                    f32x4 p1 = __builtin_amdgcn_mfma_f32_16x16x32_f16(wfA[q][1], pa1, f32x4{0,0,0,0}, 0, 0, 0);
                    acc[q] = p0 + p1;
                }
                __builtin_amdgcn_s_setprio(0);
            } else {
#pragma unroll
                for (int q = 0; q < 4; ++q) acc[q] = ai[q];
            }
            // ---- cells in-register: lane (quad,m) owns unit 16gw+4q+quad ----
            _Float16 hq[4];
#pragma unroll
            for (int q = 0; q < 4; ++q) {      // 4 independent cells
                float ig = sigm_pre(acc[q][0]), fg = sigm_pre(acc[q][1]);
                float gg = tanh_pre(acc[q][2]), og = sigm_pre(acc[q][3]);
                cst[q] = fmaf(fg, cst[q], ig * gg);
                hq[q] = (_Float16)(og * tanh_f(cst[q]));
            }
            if (m < NBat) {
                _Float16* hw = h1ring[t & 3] + hwbase;
#pragma unroll
                for (int q = 0; q < 4; ++q) hw[4 * q] = hq[q];
            }
            if (lane == 0) {          // publish: DS in-order, no waitcnt
                asm volatile("" ::: "memory");
                *(volatile int*)&flg[gw] = t + 1;
            }
        }
    } else {
        // ================= Q: L2 pipeline, self-paced =================
        f16x8 pa0{}, pa1{}, pb0{}, pb1{};
#pragma unroll 4
        for (int u = 0; u < Tt; ++u) {
            poll_flags(flg, u + 1, u, lane);   // h1(u) ready + own group done u-1
            // ---- finalize out(u-1) -> LDS outbuf (off critical path) ----
            if (u > 0 && w == 4 && lane < NBat) {
                const float* hp2 = &headp[(u - 1) & 1][lane][0];
                f32x4 s0 = *(const f32x4*)(hp2);
                f32x4 s1 = *(const f32x4*)(hp2 + 4);
                f32x4 s2 = *(const f32x4*)(hp2 + 8);
                f32x4 s3 = *(const f32x4*)(hp2 + 12);
                f32x4 sv = (s0 + s1) + (s2 + s3);
                outbuf[lane * Tt + (u - 1)] = blin + (sv[0] + sv[1]) + (sv[2] + sv[3]);
            }
            // ---- a2(u) = W2.h1(u) + W3.h2(u-1) + b2 (pre-scaled) ----
            const _Float16* h1p = h1ring[u & 3] + m * HSTR;
            const _Float16* h2p = h2buf[(u + 1) & 1] + m * HSTR;  // (u-1) parity
            if (m < NBat) {
                pa0 = *(const f16x8*)(h1p + quad * 8);
                pa1 = *(const f16x8*)(h1p + 32 + quad * 8);
                pb0 = *(const f16x8*)(h2p + quad * 8);
                pb1 = *(const f16x8*)(h2p + 32 + quad * 8);
            }
            f32x4 acc[4];
            __builtin_amdgcn_s_setprio(1);
#pragma unroll
            for (int q = 0; q < 4; ++q) {   // depth-1: 4 independent MFMAs
                f32x4 p0 = __builtin_amdgcn_mfma_f32_16x16x32_f16(wfA[q][0], pa0, bv[q], 0, 0, 0);
                f32x4 p1 = __builtin_amdgcn_mfma_f32_16x16x32_f16(wfA[q][1], pa1, f32x4{0,0,0,0}, 0, 0, 0);
                f32x4 p2 = __builtin_amdgcn_mfma_f32_16x16x32_f16(wfB[q][0], pb0, f32x4{0,0,0,0}, 0, 0, 0);
                f32x4 p3 = __builtin_amdgcn_mfma_f32_16x16x32_f16(wfB[q][1], pb1, f32x4{0,0,0,0}, 0, 0, 0);
                acc[q] = (p0 + p1) + (p2 + p3);
            }
            __builtin_amdgcn_s_setprio(0);
            // ---- cells in-register + per-lane head partial ----
            float hq[4];
#pragma unroll
            for (int q = 0; q < 4; ++q) {
                float ig = sigm_pre(acc[q][0]), fg = sigm_pre(acc[q][1]);
                float gg = tanh_pre(acc[q][2]), og = sigm_pre(acc[q][3]);
                cst[q] = fmaf(fg, cst[q], ig * gg);
                hq[q] = og * tanh_f(cst[q]);
            }
            if (m < NBat) {
                _Float16* hw = h2buf[u & 1] + hwbase;
#pragma unroll
                for (int q = 0; q < 4; ++q) hw[4 * q] = (_Float16)hq[q];
                float p = hq[0] * wlv[0];
                p = fmaf(hq[1], wlv[1], p);
                p = fmaf(hq[2], wlv[2], p);
                p = fmaf(hq[3], wlv[3], p);
                headp[u & 1][m][gw * 4 + quad] = p;
            }
            if (lane == 0) {          // publish after h2+headp writes
                asm volatile("" ::: "memory");
                *(volatile int*)&flg[4 + gw] = u + 1;
            }
        }
        // ---- tail: out(Tt-1); wait for all Q waves' step-(Tt-1) partials ----
        if (w == 4) {
            poll_flags(flg, 0, Tt, lane);     // all Q published Tt
            if (lane < NBat) {
                const float* hp2 = &headp[(Tt - 1) & 1][lane][0];
                f32x4 s0 = *(const f32x4*)(hp2);
                f32x4 s1 = *(const f32x4*)(hp2 + 4);
                f32x4 s2 = *(const f32x4*)(hp2 + 8);
                f32x4 s3 = *(const f32x4*)(hp2 + 12);
                f32x4 sv = (s0 + s1) + (s2 + s3);
                outbuf[lane * Tt + (Tt - 1)] = blin + (sv[0] + sv[1]) + (sv[2] + sv[3]);
            }
        }
    }
    __syncthreads();
    // ---- cooperative coalesced flush: LDS outbuf -> global out ----
    for (int i = tid; i < NBat * Tt; i += 512)
        st(out, (bb + (i >> 10)) * Tt + (i & 1023), outbuf[i], f32);
}

extern "C" void kernel_launch(void* const* d_in, const int* in_sizes, int n_in,
                              void* d_out, int out_size, void* d_ws, size_t ws_size,
                              hipStream_t stream)
{
    (void)in_sizes; (void)n_in; (void)out_size; (void)d_ws; (void)ws_size;
    lstm2_kernel<<<dim3(Bb / NBat), dim3(512), 0, stream>>>(
        d_in[0], d_in[1], d_in[2], d_in[3], d_in[4], d_in[5],
        d_in[6], d_in[7], d_in[8], d_in[9], d_in[10], d_out);
}

// Round 6
// 794.957 us; speedup vs baseline: 1.3282x; 1.3282x over previous
//
#include <hip/hip_runtime.h>
#include <hip/hip_bf16.h>

// LSTM2: B=1024, T=1024, H=64. R22: R20 (best, 758us) + scr-roundtrip
// elimination via BATCH-REPLICATED MFMA columns. R21's lesson: cells must
// stay 1-per-lane (16-lane x 4-serial-cells was +300us of VALU chain).
// Key idea: B operand col n carries batch n&3 (4x replication; free at
// read time -- same-address LDS broadcast). D col = n, D row = quad*4+reg
// (gate-interleaved rows) => lane (quad,m) holds in acc[m>>2] the 4 gates
// (i,f,g,o) of (batch m&3, unit 16gw+4*(m>>2)+quad): a 64-lane<->64-cell
// bijection. The scr LDS write+wait+read (~240cy chain) becomes a
// 12-cndmask register mux (~30cy). No masked lanes anywhere.
// Also: Q's W3.h2(u-1) MFMAs (own-group data) hoisted BEFORE the wait for
// P's h1(u) (split poll: qf>=u first, pf>=u+1 after) -- hidden latency.
// HSTR 72->80: frag reads (4 batch rows x 4 quads) and scattered h writes
// are <=2-way bank aliased (free, m136). Head: p*wl + shfl_xor(16,32)
// quad-reduce, store per (gw,q') from lanes<16; w4 finalize off-chain.
// Protocol (audited R19/R20, unchanged): h1ring 4-deep, P<=3 ahead;
// flg[0..3]=pf, flg[4..7]=qf; lane-0 publish after data writes (same-wave
// DS in-order). P(t): min(pf)>=t && min(qf)>=t-3. Q(u): min(qf)>=u, then
// min(pf)>=u+1. Tail: w4 polls min(qf)>=Tt before reading headp(Tt-1).
// Layouts (m89/m91/m120): A[m=lane&15][k=(lane>>4)*8+j],
// B[k=(lane>>4)*8+j][n=lane&15], C/D: row=(lane>>4)*4+reg, col=lane&15.

typedef _Float16 f16x8 __attribute__((ext_vector_type(8)));
typedef float    f32x4 __attribute__((ext_vector_type(4)));

namespace {
constexpr int Bb = 1024;
constexpr int Tt = 1024;
constexpr int NBat = 4;    // batches per block
constexpr int HSTR = 80;   // f16 stride per batch row of h (bank-tuned)
constexpr int XSTR = 1025; // f32 stride per batch row of x

// Pre-scaled activations: gate rows of W/b folded with -log2e (i,f,o) and
// -2log2e (g) at load, so no input multiply here.
__device__ __forceinline__ float sigm_pre(float a) {   // a = -1.4427*x
    return __builtin_amdgcn_rcpf(1.0f + __builtin_amdgcn_exp2f(a));
}
__device__ __forceinline__ float tanh_pre(float a) {   // a = -2.8854*x
    return fmaf(2.0f, __builtin_amdgcn_rcpf(1.0f + __builtin_amdgcn_exp2f(a)), -1.0f);
}
__device__ __forceinline__ float tanh_f(float x) {     // unscaled input (c-path)
    float e = __builtin_amdgcn_exp2f(-2.8853900817779268f * x);
    return fmaf(2.0f, __builtin_amdgcn_rcpf(1.0f + e), -1.0f);
}
// Dtype sniff (proven R2-R21).
__device__ __forceinline__ bool detect_f32(const void* w) {
    const unsigned short* p = (const unsigned short*)w;
    int sane = 0;
    for (int i = 0; i < 64; ++i) {
        int e = (p[2 * i] >> 7) & 0xFF;
        if (e >= 107 && e <= 129) ++sane;
    }
    return sane < 32;
}
__device__ __forceinline__ float ld(const void* p, int i, bool f32) {
    return f32 ? ((const float*)p)[i]
               : __bfloat162float(((const __hip_bfloat16*)p)[i]);
}
__device__ __forceinline__ void st(void* p, int i, float v, bool f32) {
    if (f32) ((float*)p)[i] = v;
    else     ((__hip_bfloat16*)p)[i] = __float2bfloat16(v);
}
// Lane-parallel spin: lane i watches flg[i&7]; P-flags (idx<4) against tp,
// Q-flags against tq. One broadcast ds_read_b32 per spin, __all ballot.
__device__ __forceinline__ void poll_flags(const int* f, int tp, int tq, int lane) {
    const int idx = lane & 7;
    const int thr = (idx < 4) ? tp : tq;
    for (;;) {
        int v = ((const volatile int*)f)[idx];
        if (__all(v >= thr)) break;
    }
    __builtin_amdgcn_sched_barrier(0);
    asm volatile("" ::: "memory");
}
} // namespace

__global__ __launch_bounds__(512, 1) void lstm2_kernel(
    const void* __restrict__ x,      // [B, T]
    const void* __restrict__ w_ih1,  // [256, 1]
    const void* __restrict__ w_hh1,  // [256, 64]
    const void* __restrict__ b_ih1,  // [256]
    const void* __restrict__ b_hh1,  // [256]
    const void* __restrict__ w_ih2,  // [256, 64]
    const void* __restrict__ w_hh2,  // [256, 64]
    const void* __restrict__ b_ih2,  // [256]
    const void* __restrict__ b_hh2,  // [256]
    const void* __restrict__ w_lin,  // [1, 64]
    const void* __restrict__ b_lin,  // [1]
    void* __restrict__ out)          // [B, T]
{
    const int tid  = threadIdx.x;
    const int lane = tid & 63;
    const int w    = tid >> 6;       // wave 0..7
    const int gw   = w & 3;          // group-local wave -> unit group 16gw..
    const bool isP = w < 4;          // P: L1 recurrence; Q: L2 pipeline
    const int m    = lane & 15;      // MFMA col
    const int quad = lane >> 4;
    const int bb   = blockIdx.x * NBat;

    const bool f32 = detect_f32(w_hh1);

    __shared__ float                  xs[NBat * XSTR];
    __shared__ __align__(16) _Float16 h1ring[4][NBat * HSTR]; // 4-deep ring
    __shared__ __align__(16) _Float16 h2buf[2][NBat * HSTR];  // parity (Q)
    __shared__ __align__(16) float    headp[2][NBat][16];     // [par][b][gw*4+q']
    __shared__ float                  outbuf[NBat * Tt];      // staged outputs
    __shared__ int                    flg[8];                 // 0..3 pf, 4..7 qf

    // ---- stage x + zero h buffers ----
    for (int i = tid; i < NBat * 1024; i += 512)
        xs[(i >> 10) * XSTR + (i & 1023)] = ld(x, (bb + (i >> 10)) * Tt + (i & 1023), f32);
    for (int i = tid; i < NBat * HSTR; i += 512) {
        h1ring[0][i] = (_Float16)0; h1ring[1][i] = (_Float16)0;
        h1ring[2][i] = (_Float16)0; h1ring[3][i] = (_Float16)0;
        h2buf[0][i] = (_Float16)0;  h2buf[1][i] = (_Float16)0;
    }
    if (tid < 8) flg[tid] = 0;

    // ---- A-fragments, gate-interleaved rows (R13), activation-scale folded ----
    // tile row (lane&15) = 4*u_loc + g -> mem row 64*g + 16*gw + 4q + u_loc
    const int arow = lane & 15;
    const int g_ld = arow & 3;
    const int u_ld = arow >> 2;
    const float scA = (g_ld == 2) ? -2.8853900817779268f : -1.4426950408889634f;
    f16x8 wfA[4][2], wfB[4][2];   // P: wfA=W1 (wfB zero); Q: wfA=W2, wfB=W3
    {
        const void* MA = isP ? w_hh1 : w_ih2;
#pragma unroll
        for (int q = 0; q < 4; ++q) {
            const int row = 64 * g_ld + 16 * gw + 4 * q + u_ld;
#pragma unroll
            for (int s = 0; s < 2; ++s) {
                const int base = row * 64 + 32 * s + quad * 8;
                if (f32) {
                    const float* A = (const float*)MA;
                    const float* B = (const float*)w_hh2;
#pragma unroll
                    for (int j = 0; j < 8; ++j) {
                        wfA[q][s][j] = (_Float16)(scA * A[base + j]);
                        wfB[q][s][j] = isP ? (_Float16)0.0f
                                           : (_Float16)(scA * B[base + j]);
                    }
                } else {
                    const __hip_bfloat16* A = (const __hip_bfloat16*)MA;
                    const __hip_bfloat16* B = (const __hip_bfloat16*)w_hh2;
#pragma unroll
                    for (int j = 0; j < 8; ++j) {
                        wfA[q][s][j] = (_Float16)(scA * __bfloat162float(A[base + j]));
                        wfB[q][s][j] = isP ? (_Float16)0.0f
                                           : (_Float16)(scA * __bfloat162float(B[base + j]));
                    }
                }
            }
        }
    }
    // bias / wx per (tile q, gate r): D row r of tile q = gate r, unit 16gw+4q+quad
    f32x4 bv[4], wxv[4];
#pragma unroll
    for (int q = 0; q < 4; ++q)
#pragma unroll
        for (int r = 0; r < 4; ++r) {
            const int row = 64 * r + 16 * gw + 4 * q + quad;
            const float sg = (r == 2) ? -2.8853900817779268f : -1.4426950408889634f;
            bv[q][r] = sg * (isP ? (ld(b_ih1, row, f32) + ld(b_hh1, row, f32))
                                 : (ld(b_ih2, row, f32) + ld(b_hh2, row, f32)));
            wxv[q][r] = isP ? sg * ld(w_ih1, row, f32) : 0.0f;
        }
    // cell ownership (batch-replicated cols): lane (quad,m) owns
    // (batch m&3, unit 16gw + 4*(m>>2) + quad), gates in acc[m>>2].
    const int q2   = m >> 2;
    const int bsel = m & 3;
    const int hidx = bsel * HSTR + 16 * gw + 4 * q2 + quad;  // own h slot
    const bool s1 = (q2 & 1) != 0, s2 = (q2 & 2) != 0;
    const float wl_u = ld(w_lin, 16 * gw + 4 * q2 + quad, f32);
    const float blin = ld(b_lin, 0, f32);
    float cst = 0.0f;                 // c-state of the owned cell
    __syncthreads();   // xs + zeroed bufs + flags visible

    if (isP) {
        // ================= P: L1 recurrence, self-paced =================
#pragma unroll 4
        for (int t = 0; t < Tt; ++t) {
            // acc-init before poll: reads only static xs/regs
            const float xt = xs[bsel * XSTR + t];
            f32x4 ai[4];
#pragma unroll
            for (int q = 0; q < 4; ++q)
#pragma unroll
                for (int r = 0; r < 4; ++r)
                    ai[q][r] = fmaf(xt, wxv[q][r], bv[q][r]);
            poll_flags(flg, t, t - 3, lane);   // group sync + ring-not-full
            f32x4 acc[4];
            if (t > 0) {
                const _Float16* hp = h1ring[(t - 1) & 3] + bsel * HSTR;
                const f16x8 pa0 = *(const f16x8*)(hp + quad * 8);
                const f16x8 pa1 = *(const f16x8*)(hp + 32 + quad * 8);
                __builtin_amdgcn_s_setprio(1);
#pragma unroll
                for (int q = 0; q < 4; ++q) {   // depth-1: independent k-halves
                    f32x4 p0 = __builtin_amdgcn_mfma_f32_16x16x32_f16(wfA[q][0], pa0, ai[q], 0, 0, 0);
                    f32x4 p1 = __builtin_amdgcn_mfma_f32_16x16x32_f16(wfA[q][1], pa1, f32x4{0,0,0,0}, 0, 0, 0);
                    acc[q] = p0 + p1;
                }
                __builtin_amdgcn_s_setprio(0);
            } else {
#pragma unroll
                for (int q = 0; q < 4; ++q) acc[q] = ai[q];
            }
            // ---- register mux: g = acc[q2] (12 cndmasks, no LDS) ----
            f32x4 g;
#pragma unroll
            for (int r = 0; r < 4; ++r) {
                float lo = s1 ? acc[1][r] : acc[0][r];
                float hi = s1 ? acc[3][r] : acc[2][r];
                g[r] = s2 ? hi : lo;
            }
            // ---- cell (1 per lane) ----
            float ig = sigm_pre(g[0]), fg = sigm_pre(g[1]);
            float gg = tanh_pre(g[2]), og = sigm_pre(g[3]);
            cst = fmaf(fg, cst, ig * gg);
            h1ring[t & 3][hidx] = (_Float16)(og * tanh_f(cst));
            if (lane == 0) {          // publish: DS in-order, no waitcnt
                asm volatile("" ::: "memory");
                *(volatile int*)&flg[gw] = t + 1;
            }
        }
    } else {
        // ================= Q: L2 pipeline, self-paced =================
#pragma unroll 4
        for (int u = 0; u < Tt; ++u) {
            poll_flags(flg, 0, u, lane);       // own group: h2(u-1)+headp(u-1)
            // ---- finalize out(u-1) -> LDS outbuf (off critical path) ----
            if (u > 0 && w == 4 && lane < NBat) {
                const float* hp2 = &headp[(u - 1) & 1][lane][0];
                f32x4 v0 = *(const f32x4*)(hp2);
                f32x4 v1 = *(const f32x4*)(hp2 + 4);
                f32x4 v2 = *(const f32x4*)(hp2 + 8);
                f32x4 v3 = *(const f32x4*)(hp2 + 12);
                f32x4 sv = (v0 + v1) + (v2 + v3);
                outbuf[lane * Tt + (u - 1)] = blin + (sv[0] + sv[1]) + (sv[2] + sv[3]);
            }
            // ---- W3.h2(u-1) half first (own-group data; hides P wait) ----
            const _Float16* h2p = h2buf[(u + 1) & 1] + bsel * HSTR; // (u-1) parity
            const f16x8 pb0 = *(const f16x8*)(h2p + quad * 8);
            const f16x8 pb1 = *(const f16x8*)(h2p + 32 + quad * 8);
            f32x4 a3[4];
            __builtin_amdgcn_s_setprio(1);
#pragma unroll
            for (int q = 0; q < 4; ++q) {
                f32x4 p2 = __builtin_amdgcn_mfma_f32_16x16x32_f16(wfB[q][0], pb0, bv[q], 0, 0, 0);
                f32x4 p3 = __builtin_amdgcn_mfma_f32_16x16x32_f16(wfB[q][1], pb1, f32x4{0,0,0,0}, 0, 0, 0);
                a3[q] = p2 + p3;
            }
            __builtin_amdgcn_s_setprio(0);
            poll_flags(flg, u + 1, 0, lane);   // h1(u) ready (P published)
            const _Float16* h1p = h1ring[u & 3] + bsel * HSTR;
            const f16x8 pa0 = *(const f16x8*)(h1p + quad * 8);
            const f16x8 pa1 = *(const f16x8*)(h1p + 32 + quad * 8);
            f32x4 acc[4];
            __builtin_amdgcn_s_setprio(1);
#pragma unroll
            for (int q = 0; q < 4; ++q) {
                f32x4 p0 = __builtin_amdgcn_mfma_f32_16x16x32_f16(wfA[q][0], pa0, a3[q], 0, 0, 0);
                f32x4 p1 = __builtin_amdgcn_mfma_f32_16x16x32_f16(wfA[q][1], pa1, f32x4{0,0,0,0}, 0, 0, 0);
                acc[q] = p0 + p1;
            }
            __builtin_amdgcn_s_setprio(0);
            // ---- register mux + cell + head partial ----
            f32x4 g;
#pragma unroll
            for (int r = 0; r < 4; ++r) {
                float lo = s1 ? acc[1][r] : acc[0][r];
                float hi = s1 ? acc[3][r] : acc[2][r];
                g[r] = s2 ? hi : lo;
            }
            float ig = sigm_pre(g[0]), fg = sigm_pre(g[1]);
            float gg = tanh_pre(g[2]), og = sigm_pre(g[3]);
            cst = fmaf(fg, cst, ig * gg);
            float h = og * tanh_f(cst);
            h2buf[u & 1][hidx] = (_Float16)h;
            float p = h * wl_u;                // reduce over quad (unit sub-dim)
            p += __shfl_xor(p, 16);
            p += __shfl_xor(p, 32);
            if (lane < 16)                     // quad==0 lanes hold quad-sum
                headp[u & 1][bsel][gw * 4 + q2] = p;
            if (lane == 0) {          // publish after h2+headp writes
                asm volatile("" ::: "memory");
                *(volatile int*)&flg[4 + gw] = u + 1;
            }
        }
        // ---- tail: out(Tt-1); wait for all Q waves' step-(Tt-1) partials ----
        if (w == 4) {
            poll_flags(flg, 0, Tt, lane);     // all Q published Tt
            if (lane < NBat) {
                const float* hp2 = &headp[(Tt - 1) & 1][lane][0];
                f32x4 v0 = *(const f32x4*)(hp2);
                f32x4 v1 = *(const f32x4*)(hp2 + 4);
                f32x4 v2 = *(const f32x4*)(hp2 + 8);
                f32x4 v3 = *(const f32x4*)(hp2 + 12);
                f32x4 sv = (v0 + v1) + (v2 + v3);
                outbuf[lane * Tt + (Tt - 1)] = blin + (sv[0] + sv[1]) + (sv[2] + sv[3]);
            }
        }
    }
    __syncthreads();
    // ---- cooperative coalesced flush: LDS outbuf -> global out ----
    for (int i = tid; i < NBat * Tt; i += 512)
        st(out, (bb + (i >> 10)) * Tt + (i & 1023), outbuf[i], f32);
}

extern "C" void kernel_launch(void* const* d_in, const int* in_sizes, int n_in,
                              void* d_out, int out_size, void* d_ws, size_t ws_size,
                              hipStream_t stream)
{
    (void)in_sizes; (void)n_in; (void)out_size; (void)d_ws; (void)ws_size;
    lstm2_kernel<<<dim3(Bb / NBat), dim3(512), 0, stream>>>(
        d_in[0], d_in[1], d_in[2], d_in[3], d_in[4], d_in[5],
        d_in[6], d_in[7], d_in[8], d_in[9], d_in[10], d_out);
}

// Round 7
// 718.034 us; speedup vs baseline: 1.4705x; 1.1071x over previous
//
#include <hip/hip_runtime.h>
#include <hip/hip_bf16.h>

// LSTM2: B=1024, T=1024, H=64. R23: R22 (795us) with Q's chain repaired.
// R22 lesson: kernel pace = max(P-chain, Q-chain); the split Q poll (2
// serial spin-detects) + head-reduce-before-publish made Q the limiter.
// Changes (Q scheduling only; P loop + protocol + mux unchanged):
//  (1) Q poll merged back to ONE spin (pf>=u+1 && qf>=u, as R20).
//  (2) Q publishes qf=u+1 right after the h2 ds_write; head partial
//      (h*wl, 4x shfl_xor, headp store) moved AFTER publish (off-chain).
//      Safe: w4's finalize reads headp at LAG 2 from a DEPTH-4 buffer --
//      same-wave DS order means qf=u' visible => headp(u'-2) visible;
//      group spread <=1 => no slot collision at depth 4.
//  (3) headp = per-wave gw-slice sums [u&3][batch][gw] (xor-reduce over
//      masks 4/8/16/32 leaves full slice-sum in every lane; lanes 0-3
//      store). w4 finalize: one f32x4 read + 3 adds + blin.
//  (4) Q MFMAs: two independent 2-deep chains (W2.h1 with bv C-in;
//      W3.h2 with 0 C-in), saving 32 v_adds vs R22's depth-1 form.
// Retained from R22: batch-replicated MFMA cols (B col n = batch n&3; lane
// (quad,m) owns cell (batch m&3, unit 16gw+4*(m>>2)+quad) in acc[m>>2];
// 12-cndmask register mux replaces the scr LDS roundtrip), HSTR=80,
// ai-init hoisted above P's poll, setprio around MFMA clusters.
// Protocol (audited R19/R20): h1ring 4-deep, P<=3 ahead; flg[0..3]=pf,
// flg[4..7]=qf; lane-0 publish after the guarded data's ds_write
// (same-wave DS in-order). P(t): min(pf)>=t && min(qf)>=t-3.
// Q(u): min(pf)>=u+1 && min(qf)>=u. Tail: w4 polls min(qf)>=Tt then
// finalizes out(Tt-2), out(Tt-1).
// Layouts (m89/m91/m120): A[m=lane&15][k=(lane>>4)*8+j],
// B[k=(lane>>4)*8+j][n=lane&15], C/D: row=(lane>>4)*4+reg, col=lane&15.

typedef _Float16 f16x8 __attribute__((ext_vector_type(8)));
typedef float    f32x4 __attribute__((ext_vector_type(4)));

namespace {
constexpr int Bb = 1024;
constexpr int Tt = 1024;
constexpr int NBat = 4;    // batches per block
constexpr int HSTR = 80;   // f16 stride per batch row of h (bank-tuned)
constexpr int XSTR = 1025; // f32 stride per batch row of x

// Pre-scaled activations: gate rows of W/b folded with -log2e (i,f,o) and
// -2log2e (g) at load, so no input multiply here.
__device__ __forceinline__ float sigm_pre(float a) {   // a = -1.4427*x
    return __builtin_amdgcn_rcpf(1.0f + __builtin_amdgcn_exp2f(a));
}
__device__ __forceinline__ float tanh_pre(float a) {   // a = -2.8854*x
    return fmaf(2.0f, __builtin_amdgcn_rcpf(1.0f + __builtin_amdgcn_exp2f(a)), -1.0f);
}
__device__ __forceinline__ float tanh_f(float x) {     // unscaled input (c-path)
    float e = __builtin_amdgcn_exp2f(-2.8853900817779268f * x);
    return fmaf(2.0f, __builtin_amdgcn_rcpf(1.0f + e), -1.0f);
}
// Dtype sniff (proven R2-R22).
__device__ __forceinline__ bool detect_f32(const void* w) {
    const unsigned short* p = (const unsigned short*)w;
    int sane = 0;
    for (int i = 0; i < 64; ++i) {
        int e = (p[2 * i] >> 7) & 0xFF;
        if (e >= 107 && e <= 129) ++sane;
    }
    return sane < 32;
}
__device__ __forceinline__ float ld(const void* p, int i, bool f32) {
    return f32 ? ((const float*)p)[i]
               : __bfloat162float(((const __hip_bfloat16*)p)[i]);
}
__device__ __forceinline__ void st(void* p, int i, float v, bool f32) {
    if (f32) ((float*)p)[i] = v;
    else     ((__hip_bfloat16*)p)[i] = __float2bfloat16(v);
}
// Lane-parallel spin: lane i watches flg[i&7]; P-flags (idx<4) against tp,
// Q-flags against tq. One broadcast ds_read_b32 per spin, __all ballot.
__device__ __forceinline__ void poll_flags(const int* f, int tp, int tq, int lane) {
    const int idx = lane & 7;
    const int thr = (idx < 4) ? tp : tq;
    for (;;) {
        int v = ((const volatile int*)f)[idx];
        if (__all(v >= thr)) break;
    }
    __builtin_amdgcn_sched_barrier(0);
    asm volatile("" ::: "memory");
}
} // namespace

__global__ __launch_bounds__(512, 1) void lstm2_kernel(
    const void* __restrict__ x,      // [B, T]
    const void* __restrict__ w_ih1,  // [256, 1]
    const void* __restrict__ w_hh1,  // [256, 64]
    const void* __restrict__ b_ih1,  // [256]
    const void* __restrict__ b_hh1,  // [256]
    const void* __restrict__ w_ih2,  // [256, 64]
    const void* __restrict__ w_hh2,  // [256, 64]
    const void* __restrict__ b_ih2,  // [256]
    const void* __restrict__ b_hh2,  // [256]
    const void* __restrict__ w_lin,  // [1, 64]
    const void* __restrict__ b_lin,  // [1]
    void* __restrict__ out)          // [B, T]
{
    const int tid  = threadIdx.x;
    const int lane = tid & 63;
    const int w    = tid >> 6;       // wave 0..7
    const int gw   = w & 3;          // group-local wave -> unit group 16gw..
    const bool isP = w < 4;          // P: L1 recurrence; Q: L2 pipeline
    const int m    = lane & 15;      // MFMA col
    const int quad = lane >> 4;
    const int bb   = blockIdx.x * NBat;

    const bool f32 = detect_f32(w_hh1);

    __shared__ float                  xs[NBat * XSTR];
    __shared__ __align__(16) _Float16 h1ring[4][NBat * HSTR]; // 4-deep ring
    __shared__ __align__(16) _Float16 h2buf[2][NBat * HSTR];  // parity (Q)
    __shared__ __align__(16) float    headp[4][NBat][4];      // [u&3][b][gw]
    __shared__ float                  outbuf[NBat * Tt];      // staged outputs
    __shared__ int                    flg[8];                 // 0..3 pf, 4..7 qf

    // ---- stage x + zero h buffers ----
    for (int i = tid; i < NBat * 1024; i += 512)
        xs[(i >> 10) * XSTR + (i & 1023)] = ld(x, (bb + (i >> 10)) * Tt + (i & 1023), f32);
    for (int i = tid; i < NBat * HSTR; i += 512) {
        h1ring[0][i] = (_Float16)0; h1ring[1][i] = (_Float16)0;
        h1ring[2][i] = (_Float16)0; h1ring[3][i] = (_Float16)0;
        h2buf[0][i] = (_Float16)0;  h2buf[1][i] = (_Float16)0;
    }
    if (tid < 8) flg[tid] = 0;

    // ---- A-fragments, gate-interleaved rows (R13), activation-scale folded ----
    // tile row (lane&15) = 4*u_loc + g -> mem row 64*g + 16*gw + 4q + u_loc
    const int arow = lane & 15;
    const int g_ld = arow & 3;
    const int u_ld = arow >> 2;
    const float scA = (g_ld == 2) ? -2.8853900817779268f : -1.4426950408889634f;
    f16x8 wfA[4][2], wfB[4][2];   // P: wfA=W1 (wfB zero); Q: wfA=W2, wfB=W3
    {
        const void* MA = isP ? w_hh1 : w_ih2;
#pragma unroll
        for (int q = 0; q < 4; ++q) {
            const int row = 64 * g_ld + 16 * gw + 4 * q + u_ld;
#pragma unroll
            for (int s = 0; s < 2; ++s) {
                const int base = row * 64 + 32 * s + quad * 8;
                if (f32) {
                    const float* A = (const float*)MA;
                    const float* B = (const float*)w_hh2;
#pragma unroll
                    for (int j = 0; j < 8; ++j) {
                        wfA[q][s][j] = (_Float16)(scA * A[base + j]);
                        wfB[q][s][j] = isP ? (_Float16)0.0f
                                           : (_Float16)(scA * B[base + j]);
                    }
                } else {
                    const __hip_bfloat16* A = (const __hip_bfloat16*)MA;
                    const __hip_bfloat16* B = (const __hip_bfloat16*)w_hh2;
#pragma unroll
                    for (int j = 0; j < 8; ++j) {
                        wfA[q][s][j] = (_Float16)(scA * __bfloat162float(A[base + j]));
                        wfB[q][s][j] = isP ? (_Float16)0.0f
                                           : (_Float16)(scA * __bfloat162float(B[base + j]));
                    }
                }
            }
        }
    }
    // bias / wx per (tile q, gate r): D row r of tile q = gate r, unit 16gw+4q+quad
    f32x4 bv[4], wxv[4];
#pragma unroll
    for (int q = 0; q < 4; ++q)
#pragma unroll
        for (int r = 0; r < 4; ++r) {
            const int row = 64 * r + 16 * gw + 4 * q + quad;
            const float sg = (r == 2) ? -2.8853900817779268f : -1.4426950408889634f;
            bv[q][r] = sg * (isP ? (ld(b_ih1, row, f32) + ld(b_hh1, row, f32))
                                 : (ld(b_ih2, row, f32) + ld(b_hh2, row, f32)));
            wxv[q][r] = isP ? sg * ld(w_ih1, row, f32) : 0.0f;
        }
    // cell ownership (batch-replicated cols): lane (quad,m) owns
    // (batch m&3, unit 16gw + 4*(m>>2) + quad), gates in acc[m>>2].
    const int q2   = m >> 2;
    const int bsel = m & 3;
    const int hidx = bsel * HSTR + 16 * gw + 4 * q2 + quad;  // own h slot
    const bool s1 = (q2 & 1) != 0, s2 = (q2 & 2) != 0;
    const float wl_u = ld(w_lin, 16 * gw + 4 * q2 + quad, f32);
    const float blin = ld(b_lin, 0, f32);
    float cst = 0.0f;                 // c-state of the owned cell
    __syncthreads();   // xs + zeroed bufs + flags visible

    if (isP) {
        // ================= P: L1 recurrence, self-paced =================
#pragma unroll 4
        for (int t = 0; t < Tt; ++t) {
            // acc-init before poll: reads only static xs/regs
            const float xt = xs[bsel * XSTR + t];
            f32x4 ai[4];
#pragma unroll
            for (int q = 0; q < 4; ++q)
#pragma unroll
                for (int r = 0; r < 4; ++r)
                    ai[q][r] = fmaf(xt, wxv[q][r], bv[q][r]);
            poll_flags(flg, t, t - 3, lane);   // group sync + ring-not-full
            f32x4 acc[4];
            if (t > 0) {
                const _Float16* hp = h1ring[(t - 1) & 3] + bsel * HSTR;
                const f16x8 pa0 = *(const f16x8*)(hp + quad * 8);
                const f16x8 pa1 = *(const f16x8*)(hp + 32 + quad * 8);
                __builtin_amdgcn_s_setprio(1);
#pragma unroll
                for (int q = 0; q < 4; ++q) {   // depth-1: independent k-halves
                    f32x4 p0 = __builtin_amdgcn_mfma_f32_16x16x32_f16(wfA[q][0], pa0, ai[q], 0, 0, 0);
                    f32x4 p1 = __builtin_amdgcn_mfma_f32_16x16x32_f16(wfA[q][1], pa1, f32x4{0,0,0,0}, 0, 0, 0);
                    acc[q] = p0 + p1;
                }
                __builtin_amdgcn_s_setprio(0);
            } else {
#pragma unroll
                for (int q = 0; q < 4; ++q) acc[q] = ai[q];
            }
            // ---- register mux: g = acc[q2] (12 cndmasks, no LDS) ----
            f32x4 g;
#pragma unroll
            for (int r = 0; r < 4; ++r) {
                float lo = s1 ? acc[1][r] : acc[0][r];
                float hi = s1 ? acc[3][r] : acc[2][r];
                g[r] = s2 ? hi : lo;
            }
            // ---- cell (1 per lane) ----
            float ig = sigm_pre(g[0]), fg = sigm_pre(g[1]);
            float gg = tanh_pre(g[2]), og = sigm_pre(g[3]);
            cst = fmaf(fg, cst, ig * gg);
            h1ring[t & 3][hidx] = (_Float16)(og * tanh_f(cst));
            if (lane == 0) {          // publish: DS in-order, no waitcnt
                asm volatile("" ::: "memory");
                *(volatile int*)&flg[gw] = t + 1;
            }
        }
    } else {
        // ================= Q: L2 pipeline, self-paced =================
#pragma unroll 4
        for (int u = 0; u < Tt; ++u) {
            poll_flags(flg, u + 1, u, lane);   // h1(u) ready + own group done u-1
            // ---- finalize out(u-2) -> LDS outbuf (lag 2, off-chain) ----
            if (u > 1 && w == 4 && lane < NBat) {
                f32x4 v = *(const f32x4*)&headp[(u - 2) & 3][lane][0];
                outbuf[lane * Tt + (u - 2)] = blin + (v[0] + v[1]) + (v[2] + v[3]);
            }
            // ---- a2(u) = W2.h1(u) + W3.h2(u-1) + b2 (pre-scaled) ----
            const _Float16* h1p = h1ring[u & 3] + bsel * HSTR;
            const _Float16* h2p = h2buf[(u + 1) & 1] + bsel * HSTR;  // (u-1) parity
            const f16x8 pa0 = *(const f16x8*)(h1p + quad * 8);
            const f16x8 pa1 = *(const f16x8*)(h1p + 32 + quad * 8);
            const f16x8 pb0 = *(const f16x8*)(h2p + quad * 8);
            const f16x8 pb1 = *(const f16x8*)(h2p + 32 + quad * 8);
            f32x4 acc[4];
            __builtin_amdgcn_s_setprio(1);
#pragma unroll
            for (int q = 0; q < 4; ++q) {   // two independent 2-deep chains
                f32x4 p2 = __builtin_amdgcn_mfma_f32_16x16x32_f16(wfA[q][0], pa0, bv[q], 0, 0, 0);
                p2 = __builtin_amdgcn_mfma_f32_16x16x32_f16(wfA[q][1], pa1, p2, 0, 0, 0);
                f32x4 p3 = __builtin_amdgcn_mfma_f32_16x16x32_f16(wfB[q][0], pb0, f32x4{0,0,0,0}, 0, 0, 0);
                p3 = __builtin_amdgcn_mfma_f32_16x16x32_f16(wfB[q][1], pb1, p3, 0, 0, 0);
                acc[q] = p2 + p3;
            }
            __builtin_amdgcn_s_setprio(0);
            // ---- register mux + cell ----
            f32x4 g;
#pragma unroll
            for (int r = 0; r < 4; ++r) {
                float lo = s1 ? acc[1][r] : acc[0][r];
                float hi = s1 ? acc[3][r] : acc[2][r];
                g[r] = s2 ? hi : lo;
            }
            float ig = sigm_pre(g[0]), fg = sigm_pre(g[1]);
            float gg = tanh_pre(g[2]), og = sigm_pre(g[3]);
            cst = fmaf(fg, cst, ig * gg);
            float h = og * tanh_f(cst);
            h2buf[u & 1][hidx] = (_Float16)h;
            if (lane == 0) {          // publish right after h2 write
                asm volatile("" ::: "memory");
                *(volatile int*)&flg[4 + gw] = u + 1;
            }
            // ---- head partial AFTER publish (off-chain; w4 reads lag-2) ----
            float p = h * wl_u;                // sum over own wave's 16 units
            p += __shfl_xor(p, 4);
            p += __shfl_xor(p, 8);
            p += __shfl_xor(p, 16);
            p += __shfl_xor(p, 32);
            if (lane < NBat)                   // lane==bsel, full slice sum
                headp[u & 3][lane][gw] = p;
        }
        // ---- tail: out(Tt-2), out(Tt-1) after all Q published Tt ----
        if (w == 4) {
            poll_flags(flg, 0, Tt, lane);
            if (lane < NBat) {
                f32x4 v2 = *(const f32x4*)&headp[(Tt - 2) & 3][lane][0];
                outbuf[lane * Tt + (Tt - 2)] = blin + (v2[0] + v2[1]) + (v2[2] + v2[3]);
                f32x4 v1 = *(const f32x4*)&headp[(Tt - 1) & 3][lane][0];
                outbuf[lane * Tt + (Tt - 1)] = blin + (v1[0] + v1[1]) + (v1[2] + v1[3]);
            }
        }
    }
    __syncthreads();
    // ---- cooperative coalesced flush: LDS outbuf -> global out ----
    for (int i = tid; i < NBat * Tt; i += 512)
        st(out, (bb + (i >> 10)) * Tt + (i & 1023), outbuf[i], f32);
}

extern "C" void kernel_launch(void* const* d_in, const int* in_sizes, int n_in,
                              void* d_out, int out_size, void* d_ws, size_t ws_size,
                              hipStream_t stream)
{
    (void)in_sizes; (void)n_in; (void)out_size; (void)d_ws; (void)ws_size;
    lstm2_kernel<<<dim3(Bb / NBat), dim3(512), 0, stream>>>(
        d_in[0], d_in[1], d_in[2], d_in[3], d_in[4], d_in[5],
        d_in[6], d_in[7], d_in[8], d_in[9], d_in[10], d_out);
}